// Round 4
// baseline (276.933 us; speedup 1.0000x reference)
//
#include <hip/hip_runtime.h>
#include <hip/hip_bf16.h>
#include <math.h>

// Problem constants
#define BQ 4
#define NQ 100
#define MQ 50
#define HWSZ 65536
#define NP 112   // padded N rows in partials (7 x 16)
#define MP 64    // padded M (4 x 16)
#define DCLAMP 13.8155106f   // logit(1-1e-6) = -logit(1e-6)
#define ONESBF2 0x3F803F80u  // two bf16 1.0s

typedef __attribute__((ext_vector_type(8))) short short8;
typedef __attribute__((ext_vector_type(4))) float f32x4;

// d = log(pm)-log(1-pm) = clamp(x, +-13.8155) EXACTLY (logit o clip o sigmoid).
// pm = sigmoid(clamp(x)); l1m = log(1-pm) = -log(1+e^xc).
__device__ __forceinline__ void xform2(float x, float& d, float& pm, float& l1m) {
    float xc = fminf(fmaxf(x, -DCLAMP), DCLAMP);
    d = xc;
    float e = __expf(xc);                       // in [1e-6, 1e6], no overflow
    float r = __builtin_amdgcn_rcpf(1.0f + e);
    pm = e * r;
    l1m = -__logf(1.0f + e);
}

// pack two floats -> two bf16 (RTNE) in one u32
__device__ __forceinline__ unsigned pk2(float a, float b) {
    __hip_bfloat162 h = __float22bfloat162_rn(float2{a, b});
    unsigned u;
    __builtin_memcpy(&u, &h, 4);
    return u;
}

// build a bf16x8 MFMA fragment from two float4
__device__ __forceinline__ short8 mk8(float4 a, float4 b) {
    union { short8 s; unsigned u[4]; } r;
    r.u[0] = pk2(a.x, a.y); r.u[1] = pk2(a.z, a.w);
    r.u[2] = pk2(b.x, b.y); r.u[3] = pk2(b.z, b.w);
    return r.s;
}

// build a bf16x8 MFMA fragment from 8 scalars
__device__ __forceinline__ short8 mk8s(float a0, float a1, float a2, float a3,
                                       float a4, float a5, float a6, float a7) {
    union { short8 s; unsigned u[4]; } r;
    r.u[0] = pk2(a0, a1); r.u[1] = pk2(a2, a3);
    r.u[2] = pk2(a4, a5); r.u[3] = pk2(a6, a7);
    return r.s;
}

// Load one k-slab (32 floats deep) into a named register stage.
__device__ __forceinline__ void load_stage(
    float4& a0, float4& a1, float4 (&bv)[4][2],
    const float* ap, const float* const (&bp)[4], int k)
{
    a0 = *(const float4*)(ap + k);
    a1 = *(const float4*)(ap + k + 4);
    #pragma unroll
    for (int mt = 0; mt < 4; mt++) {
        bv[mt][0] = *(const float4*)(bp[mt] + k);
        bv[mt][1] = *(const float4*)(bp[mt] + k + 4);
    }
}

// Consume one stage: transform A, pack, 8 MFMAs.
// ONES_ROW (ntile==6): lanes with r16>=4 (global rows 100-111, padding) feed
// an all-ones A-d fragment -> acc1 rows 100-111 = colsum(tm) = St (exact:
// tm binary bf16-exact, fp32 integer accumulate). Replaces the ts VALU sums.
// Ones-col (all waves): B col 50 (mt=3 padding col) feeds an all-ones
// fragment -> acc2 col 50 = rowsum(pm) = Sp. Replaces the rsp accumulator.
template <bool ONES_ROW>
__device__ __forceinline__ void compute_iter(
    const float4& a0, const float4& a1, const float4 (&bv)[4][2],
    f32x4 (&acc1)[4], f32x4 (&acc2)[4], float& rsl,
    bool c50, bool rge4)
{
    float d0,d1,d2,d3,d4,d5,d6,d7, p0,p1,p2,p3,p4,p5,p6,p7, l;
    xform2(a0.x, d0, p0, l); rsl += l;
    xform2(a0.y, d1, p1, l); rsl += l;
    xform2(a0.z, d2, p2, l); rsl += l;
    xform2(a0.w, d3, p3, l); rsl += l;
    xform2(a1.x, d4, p4, l); rsl += l;
    xform2(a1.y, d5, p5, l); rsl += l;
    xform2(a1.z, d6, p6, l); rsl += l;
    xform2(a1.w, d7, p7, l); rsl += l;
    short8 fd = mk8s(d0,d1,d2,d3,d4,d5,d6,d7);
    const short8 fp = mk8s(p0,p1,p2,p3,p4,p5,p6,p7);

    if (ONES_ROW) {
        union { short8 s; unsigned u[4]; } f; f.s = fd;
        f.u[0] = rge4 ? ONESBF2 : f.u[0];
        f.u[1] = rge4 ? ONESBF2 : f.u[1];
        f.u[2] = rge4 ? ONESBF2 : f.u[2];
        f.u[3] = rge4 ? ONESBF2 : f.u[3];
        fd = f.s;
    }

    #pragma unroll
    for (int mt = 0; mt < 4; mt++) {
        union { short8 s; unsigned u[4]; } fb;
        fb.s = mk8(bv[mt][0], bv[mt][1]);
        if (mt == 3) {
            fb.u[0] = c50 ? ONESBF2 : fb.u[0];
            fb.u[1] = c50 ? ONESBF2 : fb.u[1];
            fb.u[2] = c50 ? ONESBF2 : fb.u[2];
            fb.u[3] = c50 ? ONESBF2 : fb.u[3];
        }
        acc1[mt] = __builtin_amdgcn_mfma_f32_16x16x32_bf16(fd, fb.s, acc1[mt], 0, 0, 0);
        acc2[mt] = __builtin_amdgcn_mfma_f32_16x16x32_bf16(fp, fb.s, acc2[mt], 0, 0, 0);
    }
}

template <bool ONES_ROW>
__device__ __forceinline__ void run_wave(
    const float* __restrict__ pred_masks, const float* __restrict__ tgt_masks,
    float* __restrict__ part1, float* __restrict__ part2,
    float* __restrict__ rspart,
    int nch, int Kc, int chunk, int b, int ntile)
{
    const int lane = threadIdx.x;        // 1-wave blocks
    const int r16  = lane & 15;
    const int kq8  = (lane >> 4) * 8;
    const long kbase = (long)chunk * Kc;
    const bool c50  = (r16 == 2);        // B col 48+2 = 50 (mt=3 ones-col)
    const bool rge4 = (r16 >= 4);        // A rows 100-111 (ntile=6 ones-rows)

    // A pointer: operand-layout direct load (row-clamped; rows 100-111 are
    // padding -> repurposed by ONES_ROW, never read as data)
    const int arow = min(ntile * 16 + r16, NQ - 1);
    const float* ap = pred_masks + (((long)(b * NQ + arow)) << 16) + kbase + kq8;

    // B pointers, one per m-tile (mt=3 rows 50..63 clamp to 49; col 50 is
    // repurposed as the ones-col, 51..63 never read)
    const float* bp[4];
    #pragma unroll
    for (int mt = 0; mt < 4; mt++) {
        const int brow = min(mt * 16 + r16, MQ - 1);
        bp[mt] = tgt_masks + (((long)(b * MQ + brow)) << 16) + kbase + kq8;
    }

    f32x4 acc1[4], acc2[4];
    #pragma unroll
    for (int mt = 0; mt < 4; mt++) {
        acc1[mt] = (f32x4){0.f, 0.f, 0.f, 0.f};
        acc2[mt] = (f32x4){0.f, 0.f, 0.f, 0.f};
    }
    float rsl = 0.f;

    // 2-deep register pipeline: named even/odd stages, loads for iter s+2
    // issue while iter s computes (+iter s+1 in between) -> ~1.5-2 iters of
    // load-latency cover per wave, no LDS, no barriers.
    float4 A00, A01, B0[4][2], A10, A11, B1[4][2];
    const int nsteps = Kc / 32;          // even (Kc = 65536/nch, nch pow2 <= 128)
    load_stage(A00, A01, B0, ap, bp, 0);
    load_stage(A10, A11, B1, ap, bp, 32);

    for (int s = 0; s < nsteps; s += 2) {
        compute_iter<ONES_ROW>(A00, A01, B0, acc1, acc2, rsl, c50, rge4);
        if (s + 2 < nsteps) load_stage(A00, A01, B0, ap, bp, (s + 2) * 32);
        compute_iter<ONES_ROW>(A10, A11, B1, acc1, acc2, rsl, c50, rge4);
        if (s + 3 < nsteps) load_stage(A10, A11, B1, ap, bp, (s + 3) * 32);
    }

    // ---- store C partials: C/D layout col=lane&15, row=(lane>>4)*4+reg ----
    const long pbase = ((long)(b * nch + chunk)) * NP * MP;
    const int nr0 = (lane >> 4) * 4;
    #pragma unroll
    for (int mt = 0; mt < 4; mt++) {
        const int mloc = mt * 16 + r16;
        #pragma unroll
        for (int r = 0; r < 4; r++) {
            const int ng = ntile * 16 + nr0 + r;
            part1[pbase + ng * MP + mloc] = acc1[mt][r];
            part2[pbase + ng * MP + mloc] = acc2[mt][r];
        }
    }

    // ---- rsl row sums: lanes {r,r+16,r+32,r+48} hold row r's k-partials ----
    rsl += __shfl_xor(rsl, 16); rsl += __shfl_xor(rsl, 32);
    if (lane < 16)
        rspart[(long)(b * nch + chunk) * NP + ntile * 16 + lane] = rsl;
}

// 1-wave workgroups; each wave fully independent (no LDS, no barriers).
// launch_bounds(64,3): VGPR cap ~170 (stages need ~150); forcing tighter
// caused the round-1 spill disaster.
__global__ __launch_bounds__(64, 3)
void matcher_main(const float* __restrict__ pred_masks,  // [4][100][65536]
                  const float* __restrict__ tgt_masks,   // [4][50][65536]
                  float* __restrict__ part1,             // [4][nch][112][64]
                  float* __restrict__ part2,             // [4][nch][112][64]
                  float* __restrict__ rspart,            // [4][nch][112]
                  int nch, int Kc)
{
    const int chunk = blockIdx.x;
    const int b     = blockIdx.y;
    const int ntile = blockIdx.z;        // 0..6
    if (ntile == 6)
        run_wave<true>(pred_masks, tgt_masks, part1, part2, rspart, nch, Kc, chunk, b, 6);
    else
        run_wave<false>(pred_masks, tgt_masks, part1, part2, rspart, nch, Kc, chunk, b, ntile);
}

// Epilogue: one block per (b,n), 1024 threads; 16-way chunk-group reduction.
// St comes from part1 row 100 (ones-row trick); Sp from part2 col 50
// (ones-col trick); rspart carries only rsl.
__global__ __launch_bounds__(1024)
void matcher_epilogue(const float* __restrict__ pred_logits, // [4][100][2]
                      const float* __restrict__ pred_style,  // [4][100][4]
                      const int*   __restrict__ styles,      // [4][50]
                      const float* __restrict__ part1,
                      const float* __restrict__ part2,
                      const float* __restrict__ rspart,
                      float* __restrict__ out, int nch)
{
    __shared__ float red1[16][64], red2[16][64], redt[16][64];
    __shared__ float slw[16];

    const int blk = blockIdx.x;          // 0..399
    const int b = blk / NQ, n = blk % NQ;
    const int t = threadIdx.x;
    const int m = t & 63, cg = t >> 6;   // cg in 0..15

    float S1 = 0.f, S2 = 0.f, St = 0.f;
    for (int c = cg; c < nch; c += 16) {
        const long cb = (long)(b * nch + c) * NP;
        S1 += part1[(cb + n) * MP + m];
        S2 += part2[(cb + n) * MP + m];
        St += part1[(cb + 100) * MP + m];   // ones-row: colsum(tm), exact
    }
    red1[cg][m] = S1; red2[cg][m] = S2; redt[cg][m] = St;

    // Sl across chunks: threads 0..nch-1 load, per-wave shuffle reduce
    float sl = 0.f;
    if (t < nch)
        sl = rspart[(long)(b * nch + t) * NP + n];
    #pragma unroll
    for (int off = 32; off; off >>= 1) sl += __shfl_down(sl, off);
    if ((t & 63) == 0) slw[t >> 6] = sl;
    __syncthreads();

    if (t < MQ) {
        float Sl = 0.f, Sp = 0.f, s1 = 0.f, s2 = 0.f, st = 0.f;
        #pragma unroll
        for (int w = 0; w < 16; w++) {
            Sl += slw[w];
            Sp += red2[w][50];              // ones-col: rowsum(pm)
            s1 += red1[w][t]; s2 += red2[w][t]; st += redt[w][t];
        }

        // classification: -softmax(logits)[1]
        const float l0 = pred_logits[(b * NQ + n) * 2 + 0];
        const float l1 = pred_logits[(b * NQ + n) * 2 + 1];
        const float p1 = 1.0f / (1.0f + __expf(l0 - l1));

        // style: -softmax(style)[sid]
        const float* stp = &pred_style[(b * NQ + n) * 4];
        const float v0 = stp[0], v1 = stp[1], v2 = stp[2], v3 = stp[3];
        const float mx = fmaxf(fmaxf(v0, v1), fmaxf(v2, v3));
        const float e0 = __expf(v0 - mx), e1 = __expf(v1 - mx),
                    e2 = __expf(v2 - mx), e3 = __expf(v3 - mx);
        const float esum = e0 + e1 + e2 + e3;
        int sid = styles[b * MQ + t];
        sid = min(max(sid, 0), 3);
        const float ps = (sid == 0 ? e0 : sid == 1 ? e1 : sid == 2 ? e2 : e3) / esum;

        const float cost_mask = -(s1 + Sl) * (1.0f / (float)HWSZ);
        const float dice = 1.0f - (2.0f * s2 + 1.0f) / (Sp + st + 1.0f);

        float c = 2.0f * (-p1) + 5.0f * cost_mask + 5.0f * dice + 1.0f * (-ps);
        if (isnan(c)) c = 10000.0f;
        else if (isinf(c)) c = (c > 0.f) ? 10000.0f : -10000.0f;
        out[(b * NQ + n) * MQ + t] = c;
    }
}

extern "C" void kernel_launch(void* const* d_in, const int* in_sizes, int n_in,
                              void* d_out, int out_size, void* d_ws, size_t ws_size,
                              hipStream_t stream) {
    const float* pred_logits = (const float*)d_in[0];
    const float* pred_masks  = (const float*)d_in[1];
    const float* pred_style  = (const float*)d_in[2];
    const float* tgt_masks   = (const float*)d_in[3];
    const int*   styles      = (const int*)d_in[4];
    float* out = (float*)d_out;

    // ws layout: part1/part2 [4][nch][112][64], rspart [4][nch][112]
    int nch = 8;
    for (int cand = 128; cand >= 8; cand >>= 1) {
        size_t need = (size_t)cand * (2ull * BQ * NP * MP * 4ull
                                      + (size_t)BQ * NP * 4ull);
        if (need <= ws_size) { nch = cand; break; }
    }
    const int Kc = HWSZ / nch;

    float* part1  = (float*)d_ws;
    float* part2  = part1 + (size_t)BQ * nch * NP * MP;
    float* rspart = part2 + (size_t)BQ * nch * NP * MP;

    dim3 grid(nch, BQ, 7);
    matcher_main<<<grid, 64, 0, stream>>>(pred_masks, tgt_masks, part1, part2, rspart, nch, Kc);

    matcher_epilogue<<<BQ * NQ, 1024, 0, stream>>>(
        pred_logits, pred_style, styles, part1, part2, rspart, out, nch);
}

// Round 5
// 227.939 us; speedup vs baseline: 1.2149x; 1.2149x over previous
//
#include <hip/hip_runtime.h>
#include <hip/hip_bf16.h>
#include <math.h>

// Problem constants
#define BQ 4
#define NQ 100
#define MQ 50
#define HWSZ 65536
#define NP 112   // padded N rows in partials (7 x 16)
#define MP 64    // padded M (4 x 16)
#define DCLAMP 13.8155106f   // logit(1-1e-6) = -logit(1e-6)
#define ONESBF2 0x3F803F80u  // two bf16 1.0s

typedef __attribute__((ext_vector_type(8))) short short8;
typedef __attribute__((ext_vector_type(4))) float f32x4;

// d = log(pm)-log(1-pm) = clamp(x, +-13.8155) EXACTLY (logit o clip o sigmoid).
// pm = sigmoid(clamp(x)); l1m = log(1-pm) = -log(1+e^xc).
__device__ __forceinline__ void xform2(float x, float& d, float& pm, float& l1m) {
    float xc = fminf(fmaxf(x, -DCLAMP), DCLAMP);
    d = xc;
    float e = __expf(xc);                       // in [1e-6, 1e6], no overflow
    float r = __builtin_amdgcn_rcpf(1.0f + e);
    pm = e * r;
    l1m = -__logf(1.0f + e);
}

// pack two floats -> two bf16 (RTNE) in one u32
__device__ __forceinline__ unsigned pk2(float a, float b) {
    __hip_bfloat162 h = __float22bfloat162_rn(float2{a, b});
    unsigned u;
    __builtin_memcpy(&u, &h, 4);
    return u;
}

// build a bf16x8 MFMA fragment from two float4
__device__ __forceinline__ short8 mk8(float4 a, float4 b) {
    union { short8 s; unsigned u[4]; } r;
    r.u[0] = pk2(a.x, a.y); r.u[1] = pk2(a.z, a.w);
    r.u[2] = pk2(b.x, b.y); r.u[3] = pk2(b.z, b.w);
    return r.s;
}

// build a bf16x8 MFMA fragment from 8 scalars
__device__ __forceinline__ short8 mk8s(float a0, float a1, float a2, float a3,
                                       float a4, float a5, float a6, float a7) {
    union { short8 s; unsigned u[4]; } r;
    r.u[0] = pk2(a0, a1); r.u[1] = pk2(a2, a3);
    r.u[2] = pk2(a4, a5); r.u[3] = pk2(a6, a7);
    return r.s;
}

// Load one k-slab (32 floats deep) into a named register stage.
__device__ __forceinline__ void load_stage(
    float4& a0, float4& a1, float4 (&bv)[4][2],
    const float* ap, const float* const (&bp)[4], int k)
{
    a0 = *(const float4*)(ap + k);
    a1 = *(const float4*)(ap + k + 4);
    #pragma unroll
    for (int mt = 0; mt < 4; mt++) {
        bv[mt][0] = *(const float4*)(bp[mt] + k);
        bv[mt][1] = *(const float4*)(bp[mt] + k + 4);
    }
}

// Consume one stage: transform A, pack, 8 MFMAs.
// ONES_ROW (ntile==6): lanes with r16>=4 (global rows 100-111, padding) feed
// an all-ones A-d fragment -> acc1 rows 100-111 = colsum(tm) = St (exact:
// tm binary bf16-exact, fp32 integer accumulate). Replaces the ts VALU sums.
// Ones-col (all waves): B col 50 (mt=3 padding col) feeds an all-ones
// fragment -> acc2 col 50 = rowsum(pm) = Sp. Replaces the rsp accumulator.
template <bool ONES_ROW>
__device__ __forceinline__ void compute_iter(
    const float4& a0, const float4& a1, const float4 (&bv)[4][2],
    f32x4 (&acc1)[4], f32x4 (&acc2)[4], float& rsl,
    bool c50, bool rge4)
{
    float d0,d1,d2,d3,d4,d5,d6,d7, p0,p1,p2,p3,p4,p5,p6,p7, l;
    xform2(a0.x, d0, p0, l); rsl += l;
    xform2(a0.y, d1, p1, l); rsl += l;
    xform2(a0.z, d2, p2, l); rsl += l;
    xform2(a0.w, d3, p3, l); rsl += l;
    xform2(a1.x, d4, p4, l); rsl += l;
    xform2(a1.y, d5, p5, l); rsl += l;
    xform2(a1.z, d6, p6, l); rsl += l;
    xform2(a1.w, d7, p7, l); rsl += l;
    short8 fd = mk8s(d0,d1,d2,d3,d4,d5,d6,d7);
    const short8 fp = mk8s(p0,p1,p2,p3,p4,p5,p6,p7);

    if (ONES_ROW) {
        union { short8 s; unsigned u[4]; } f; f.s = fd;
        f.u[0] = rge4 ? ONESBF2 : f.u[0];
        f.u[1] = rge4 ? ONESBF2 : f.u[1];
        f.u[2] = rge4 ? ONESBF2 : f.u[2];
        f.u[3] = rge4 ? ONESBF2 : f.u[3];
        fd = f.s;
    }

    #pragma unroll
    for (int mt = 0; mt < 4; mt++) {
        union { short8 s; unsigned u[4]; } fb;
        fb.s = mk8(bv[mt][0], bv[mt][1]);
        if (mt == 3) {
            fb.u[0] = c50 ? ONESBF2 : fb.u[0];
            fb.u[1] = c50 ? ONESBF2 : fb.u[1];
            fb.u[2] = c50 ? ONESBF2 : fb.u[2];
            fb.u[3] = c50 ? ONESBF2 : fb.u[3];
        }
        acc1[mt] = __builtin_amdgcn_mfma_f32_16x16x32_bf16(fd, fb.s, acc1[mt], 0, 0, 0);
        acc2[mt] = __builtin_amdgcn_mfma_f32_16x16x32_bf16(fp, fb.s, acc2[mt], 0, 0, 0);
    }
}

template <bool ONES_ROW>
__device__ __forceinline__ void run_wave(
    const float* __restrict__ pred_masks, const float* __restrict__ tgt_masks,
    float* __restrict__ part1, float* __restrict__ part2,
    float* __restrict__ rspart,
    int nch, int Kc, int chunk, int b, int ntile)
{
    const int lane = threadIdx.x;        // 1-wave blocks
    const int r16  = lane & 15;
    const int kq8  = (lane >> 4) * 8;
    const long kbase = (long)chunk * Kc;
    const bool c50  = (r16 == 2);        // B col 48+2 = 50 (mt=3 ones-col)
    const bool rge4 = (r16 >= 4);        // A rows 100-111 (ntile=6 ones-rows)

    // A pointer: operand-layout direct load (row-clamped; rows 100-111 are
    // padding -> repurposed by ONES_ROW, never read as data)
    const int arow = min(ntile * 16 + r16, NQ - 1);
    const float* ap = pred_masks + (((long)(b * NQ + arow)) << 16) + kbase + kq8;

    // B pointers, one per m-tile (mt=3 rows 50..63 clamp to 49; col 50 is
    // repurposed as the ones-col, 51..63 never read)
    const float* bp[4];
    #pragma unroll
    for (int mt = 0; mt < 4; mt++) {
        const int brow = min(mt * 16 + r16, MQ - 1);
        bp[mt] = tgt_masks + (((long)(b * MQ + brow)) << 16) + kbase + kq8;
    }

    f32x4 acc1[4], acc2[4];
    #pragma unroll
    for (int mt = 0; mt < 4; mt++) {
        acc1[mt] = (f32x4){0.f, 0.f, 0.f, 0.f};
        acc2[mt] = (f32x4){0.f, 0.f, 0.f, 0.f};
    }
    float rsl = 0.f;

    // 2-deep register pipeline: named even/odd stages, loads for iter s+2
    // issue while iter s computes -> ~2 compute-iters (~1400 cy) of latency
    // cover per wave, no LDS, no barriers. Needs ~160-190 VGPR live; the
    // waves_per_eu(2,2) attribute on the kernel guarantees the allocator
    // doesn't squeeze below that (round-4: squeezed to 84 -> 75 MB spill).
    float4 A00, A01, B0[4][2], A10, A11, B1[4][2];
    const int nsteps = Kc / 32;          // even (Kc = 65536/nch, nch pow2 <= 128)
    load_stage(A00, A01, B0, ap, bp, 0);
    load_stage(A10, A11, B1, ap, bp, 32);

    for (int s = 0; s < nsteps; s += 2) {
        compute_iter<ONES_ROW>(A00, A01, B0, acc1, acc2, rsl, c50, rge4);
        if (s + 2 < nsteps) load_stage(A00, A01, B0, ap, bp, (s + 2) * 32);
        compute_iter<ONES_ROW>(A10, A11, B1, acc1, acc2, rsl, c50, rge4);
        if (s + 3 < nsteps) load_stage(A10, A11, B1, ap, bp, (s + 3) * 32);
    }

    // ---- store C partials: C/D layout col=lane&15, row=(lane>>4)*4+reg ----
    const long pbase = ((long)(b * nch + chunk)) * NP * MP;
    const int nr0 = (lane >> 4) * 4;
    #pragma unroll
    for (int mt = 0; mt < 4; mt++) {
        const int mloc = mt * 16 + r16;
        #pragma unroll
        for (int r = 0; r < 4; r++) {
            const int ng = ntile * 16 + nr0 + r;
            part1[pbase + ng * MP + mloc] = acc1[mt][r];
            part2[pbase + ng * MP + mloc] = acc2[mt][r];
        }
    }

    // ---- rsl row sums: lanes {r,r+16,r+32,r+48} hold row r's k-partials ----
    rsl += __shfl_xor(rsl, 16); rsl += __shfl_xor(rsl, 32);
    if (lane < 16)
        rspart[(long)(b * nch + chunk) * NP + ntile * 16 + lane] = rsl;
}

// 1-wave workgroups; each wave fully independent (no LDS, no barriers).
// amdgpu_waves_per_eu(2,2): pin occupancy target at 2 waves/EU -> VGPR
// budget 256, and (critically) the MAX of 2 stops the allocator from
// squeezing registers to chase occupancy. Round-2/3 (squeeze to 60 VGPR)
// serialized the per-iter loads -> latency-bound at 30% VALU; round-4
// (squeeze to 84) spilled the pipeline (+75 MB scratch writes). ILP from
// the 2-deep pipeline replaces TLP: 20 loads in flight covers ~2 iters.
__global__ __launch_bounds__(64)
__attribute__((amdgpu_waves_per_eu(2, 2)))
void matcher_main(const float* __restrict__ pred_masks,  // [4][100][65536]
                  const float* __restrict__ tgt_masks,   // [4][50][65536]
                  float* __restrict__ part1,             // [4][nch][112][64]
                  float* __restrict__ part2,             // [4][nch][112][64]
                  float* __restrict__ rspart,            // [4][nch][112]
                  int nch, int Kc)
{
    const int chunk = blockIdx.x;
    const int b     = blockIdx.y;
    const int ntile = blockIdx.z;        // 0..6
    if (ntile == 6)
        run_wave<true>(pred_masks, tgt_masks, part1, part2, rspart, nch, Kc, chunk, b, 6);
    else
        run_wave<false>(pred_masks, tgt_masks, part1, part2, rspart, nch, Kc, chunk, b, ntile);
}

// Epilogue: one block per (b,n), 1024 threads; 16-way chunk-group reduction.
// St comes from part1 row 100 (ones-row trick); Sp from part2 col 50
// (ones-col trick); rspart carries only rsl.
__global__ __launch_bounds__(1024)
void matcher_epilogue(const float* __restrict__ pred_logits, // [4][100][2]
                      const float* __restrict__ pred_style,  // [4][100][4]
                      const int*   __restrict__ styles,      // [4][50]
                      const float* __restrict__ part1,
                      const float* __restrict__ part2,
                      const float* __restrict__ rspart,
                      float* __restrict__ out, int nch)
{
    __shared__ float red1[16][64], red2[16][64], redt[16][64];
    __shared__ float slw[16];

    const int blk = blockIdx.x;          // 0..399
    const int b = blk / NQ, n = blk % NQ;
    const int t = threadIdx.x;
    const int m = t & 63, cg = t >> 6;   // cg in 0..15

    float S1 = 0.f, S2 = 0.f, St = 0.f;
    for (int c = cg; c < nch; c += 16) {
        const long cb = (long)(b * nch + c) * NP;
        S1 += part1[(cb + n) * MP + m];
        S2 += part2[(cb + n) * MP + m];
        St += part1[(cb + 100) * MP + m];   // ones-row: colsum(tm), exact
    }
    red1[cg][m] = S1; red2[cg][m] = S2; redt[cg][m] = St;

    // Sl across chunks: threads 0..nch-1 load, per-wave shuffle reduce
    float sl = 0.f;
    if (t < nch)
        sl = rspart[(long)(b * nch + t) * NP + n];
    #pragma unroll
    for (int off = 32; off; off >>= 1) sl += __shfl_down(sl, off);
    if ((t & 63) == 0) slw[t >> 6] = sl;
    __syncthreads();

    if (t < MQ) {
        float Sl = 0.f, Sp = 0.f, s1 = 0.f, s2 = 0.f, st = 0.f;
        #pragma unroll
        for (int w = 0; w < 16; w++) {
            Sl += slw[w];
            Sp += red2[w][50];              // ones-col: rowsum(pm)
            s1 += red1[w][t]; s2 += red2[w][t]; st += redt[w][t];
        }

        // classification: -softmax(logits)[1]
        const float l0 = pred_logits[(b * NQ + n) * 2 + 0];
        const float l1 = pred_logits[(b * NQ + n) * 2 + 1];
        const float p1 = 1.0f / (1.0f + __expf(l0 - l1));

        // style: -softmax(style)[sid]
        const float* stp = &pred_style[(b * NQ + n) * 4];
        const float v0 = stp[0], v1 = stp[1], v2 = stp[2], v3 = stp[3];
        const float mx = fmaxf(fmaxf(v0, v1), fmaxf(v2, v3));
        const float e0 = __expf(v0 - mx), e1 = __expf(v1 - mx),
                    e2 = __expf(v2 - mx), e3 = __expf(v3 - mx);
        const float esum = e0 + e1 + e2 + e3;
        int sid = styles[b * MQ + t];
        sid = min(max(sid, 0), 3);
        const float ps = (sid == 0 ? e0 : sid == 1 ? e1 : sid == 2 ? e2 : e3) / esum;

        const float cost_mask = -(s1 + Sl) * (1.0f / (float)HWSZ);
        const float dice = 1.0f - (2.0f * s2 + 1.0f) / (Sp + st + 1.0f);

        float c = 2.0f * (-p1) + 5.0f * cost_mask + 5.0f * dice + 1.0f * (-ps);
        if (isnan(c)) c = 10000.0f;
        else if (isinf(c)) c = (c > 0.f) ? 10000.0f : -10000.0f;
        out[(b * NQ + n) * MQ + t] = c;
    }
}

extern "C" void kernel_launch(void* const* d_in, const int* in_sizes, int n_in,
                              void* d_out, int out_size, void* d_ws, size_t ws_size,
                              hipStream_t stream) {
    const float* pred_logits = (const float*)d_in[0];
    const float* pred_masks  = (const float*)d_in[1];
    const float* pred_style  = (const float*)d_in[2];
    const float* tgt_masks   = (const float*)d_in[3];
    const int*   styles      = (const int*)d_in[4];
    float* out = (float*)d_out;

    // ws layout: part1/part2 [4][nch][112][64], rspart [4][nch][112]
    int nch = 8;
    for (int cand = 128; cand >= 8; cand >>= 1) {
        size_t need = (size_t)cand * (2ull * BQ * NP * MP * 4ull
                                      + (size_t)BQ * NP * 4ull);
        if (need <= ws_size) { nch = cand; break; }
    }
    const int Kc = HWSZ / nch;

    float* part1  = (float*)d_ws;
    float* part2  = part1 + (size_t)BQ * nch * NP * MP;
    float* rspart = part2 + (size_t)BQ * nch * NP * MP;

    dim3 grid(nch, BQ, 7);
    matcher_main<<<grid, 64, 0, stream>>>(pred_masks, tgt_masks, part1, part2, rspart, nch, Kc);

    matcher_epilogue<<<BQ * NQ, 1024, 0, stream>>>(
        pred_logits, pred_style, styles, part1, part2, rspart, out, nch);
}